// Round 5
// baseline (337.692 us; speedup 1.0000x reference)
//
#include <hip/hip_runtime.h>

// MRGCO: real-FFT tensor-product RGCN layer.
// real(fft) along k (len 8) = rank-5 cosine transform (j and 8-j rows equal);
// the ifft->fft round-trip between the two tensor products cancels exactly.
//
// Pipeline (2 kernels + flag memset):
//   k_fused : ONE kernel, 320 blocks, producer/consumer overlap.
//             blocks [160,320) = producers: Wft, then X/A transform units in
//             m-chunk-major order (8 chunks x 256 m-cols); each chunk published
//             via __threadfence() + device-scope atomicAdd(flags[c]).
//             blocks [0,160) = gemm consumers: C1_j = Af_j @ Xft_j (K=2048,
//             2-deep LDS ring); prefetch of each new m-chunk gated on
//             flags[c]==64 + acquire __threadfence() (cross-XCD safe: RMW
//             polls go to the coherent point; fence invalidates local L2).
//             GEMM streams K as it is produced -> makespan ~= T_transform + eps
//             instead of T_transform + T_gemm.
//   gemm_fc : out[n][h][k] = sum_j c_jk * (C1_j @ Wft_j)[n][h]  (combine fused)
//
// Swizzle: logical (row r, col c) of a K-contiguous operand stored at
//   r*K + (c&~63) + ((((c>>3)&7) ^ (r&7))<<3) + (c&7)
// so a LINEAR wave-uniform global_load_lds DMA lands tiles in LDS already
// bank-swizzled; ds_read_b128 fragment reads stay conflict-free.
//
// Residency proof (no cooperative launch needed, no deadlock possible):
// LDS 64 KB/block -> 2 blocks/CU; __launch_bounds__(256,2) caps VGPR for
// 2 waves/SIMD; 8 waves/CU << 32. Capacity 512 blocks >= grid 320, so every
// block is resident from dispatch; producers always make progress.

typedef __bf16 bf16_t;
typedef __bf16 bf16x8 __attribute__((ext_vector_type(8)));
typedef float f32x4 __attribute__((ext_vector_type(4)));

#define R2C 0.70710678118654752f

__device__ __forceinline__ size_t swz(int r, int c, int K) {
  return (size_t)r * K + (c & ~63) + ((((c >> 3) & 7) ^ (r & 7)) << 3) + (c & 7);
}

__device__ __forceinline__ void async_cp16(const void* g, void* l) {
  __builtin_amdgcn_global_load_lds((const __attribute__((address_space(1))) char*)g,
                                   (__attribute__((address_space(3))) char*)l,
                                   16, 0, 0);
}

__device__ __forceinline__ void fwd5(const float x[8], float F[5]) {
  float s04 = x[0] + x[4], d04 = x[0] - x[4];
  float s26 = x[2] + x[6];
  float s15 = x[1] + x[5], s37 = x[3] + x[7];
  float t = (x[1] + x[7]) - (x[3] + x[5]);
  float e = s04 + s26, o = s15 + s37;
  F[0] = e + o;
  F[1] = d04 + R2C * t;
  F[2] = s04 - s26;
  F[3] = d04 - R2C * t;
  F[4] = e - o;
}

// Fused producer/consumer kernel. See header comment.
// flags[c] target = 64: 32 X-units + 32 A-units per m-chunk c.
__global__ __launch_bounds__(256, 2) void k_fused(
    const float* __restrict__ X, const float* __restrict__ A,
    const float* __restrict__ W, bf16_t* __restrict__ Xft,
    bf16_t* __restrict__ Af, bf16_t* __restrict__ Wft,
    bf16_t* __restrict__ C1, int* __restrict__ flags) {
  __shared__ bf16_t sm[32768];  // 64 KB: gemm ring A[2x8192] | B[2x8192]
  const int tid = threadIdx.x;
  const int b = blockIdx.x;

  if (b >= 160) {
    // ================= PRODUCER =================
    const int pid = b - 160;  // 0..159

    // ---- Wft (tiny; ungated — consumed only by the NEXT kernel) ----
    for (int h = pid; h < 256; h += 160) {
      const float4* p = (const float4*)(W + ((size_t)tid * 256 + h) * 8);
      float4 a = p[0], bb = p[1];
      float x[8] = {a.x, a.y, a.z, a.w, bb.x, bb.y, bb.z, bb.w};
      float F[5];
      fwd5(x, F);
      const float sc[5] = {0.125f, 0.25f, 0.25f, 0.25f, 0.125f};
      size_t pos = swz(h, tid, 256);
#pragma unroll
      for (int j = 0; j < 5; j++)
        Wft[(size_t)j * 65536 + pos] = (bf16_t)(F[j] * sc[j]);
    }

    // ---- X/A units, m-chunk-major: v = c*64 + i ; i<32: X-unit, else A-unit.
    // Coverage: pid strides 160 over [0,512) — every unit done exactly once.
    bf16_t(*tx)[256] = (bf16_t(*)[256])sm;  // X transpose staging (20 KB)
    for (int v = pid; v < 512; v += 160) {
      int c = v >> 6, i = v & 63;
      if (i < 32) {
        // X-unit: Xft[j][h0..h0+8][m0..m0+256], swizzled 16B chunks via LDS.
        int m0 = c * 256, h0 = i * 8;
        const float4* p = (const float4*)(X + (((size_t)(m0 + tid) * 256) + h0) * 8);
#pragma unroll
        for (int h = 0; h < 8; h++) {
          float4 a = p[2 * h], bb = p[2 * h + 1];
          float x[8] = {a.x, a.y, a.z, a.w, bb.x, bb.y, bb.z, bb.w};
          float F[5];
          fwd5(x, F);
#pragma unroll
          for (int j = 0; j < 5; j++) tx[j * 8 + h][tid] = (bf16_t)F[j];
        }
        __syncthreads();
#pragma unroll
        for (int it = 0; it < 5; it++) {
          int slot = it * 256 + tid;
          int row = slot >> 5, ch = slot & 31;
          int j = row >> 3, hl = row & 7;
          int h = h0 + hl;
          size_t gpos = (size_t)j * 524288 + (size_t)h * 2048 + m0 +
                        ((ch & ~7) << 3) + (((ch & 7) ^ (h & 7)) << 3);
          *(uint4*)(Xft + gpos) = *(const uint4*)(&tx[row][ch * 8]);
        }
      } else {
        // A-unit: Af[j][n0..n0+64][c*256..c*256+256], 16B swizzled stores.
        int n0 = (i - 32) * 64, mb = c * 256;
#pragma unroll
        for (int w = 0; w < 8; w++) {
          int tw = w * 256 + tid;
          int n = n0 + (tw >> 5), m0u = mb + (tw & 31) * 8;
          const float4* p = (const float4*)(A + ((size_t)n * 2048 + m0u) * 8);
          float F[8][5];
#pragma unroll
          for (int u = 0; u < 8; u++) {
            float4 a = p[2 * u], bq = p[2 * u + 1];
            float x[8] = {a.x, a.y, a.z, a.w, bq.x, bq.y, bq.z, bq.w};
            fwd5(x, F[u]);
          }
          size_t pos = (size_t)n * 2048 + (m0u & ~63) +
                       ((((m0u >> 3) & 7) ^ (n & 7)) << 3);
#pragma unroll
          for (int j = 0; j < 5; j++) {
            bf16x8 vv;
#pragma unroll
            for (int u = 0; u < 8; u++) vv[u] = (bf16_t)F[u][j];
            *(bf16x8*)(Af + (size_t)j * 4194304 + pos) = vv;
          }
        }
      }
      // publish: compiler drains vmcnt(0) before s_barrier, so all waves'
      // stores are in the memory system; release fence + device-scope RMW.
      __syncthreads();
      if (tid == 0) {
        __threadfence();
        atomicAdd(&flags[c], 1);
      }
    }
  } else {
    // ================= GEMM CONSUMER (C1_j = Af_j @ Xft_j) =================
    const int j = b >> 5, y = (b >> 4) & 1, x = b & 15;
    const bf16_t* Aj = Af + (size_t)j * 4194304;
    const bf16_t* Bj = Xft + (size_t)j * 524288;
    bf16_t* Cj = C1 + (size_t)j * 524288;
    const int n0 = x * 128, h0 = y * 128;
    const int wv = tid >> 6, ln = tid & 63;
    const int quad = ln >> 4, l16 = ln & 15;
    const int wn = (wv & 1) * 64, wh = (wv >> 1) * 64;

    const bf16_t* ga[4];
    const bf16_t* gb[4];
    int lo[4];
#pragma unroll
    for (int s = 0; s < 4; s++) {
      int slot = s * 256 + tid;
      int row = slot >> 3, c16 = slot & 7;
      ga[s] = Aj + (size_t)(n0 + row) * 2048 + c16 * 8;
      gb[s] = Bj + (size_t)(h0 + row) * 2048 + c16 * 8;
      lo[s] = (s * 256 + wv * 64) * 8;
    }

    // gate chunk 0, then prologue DMA of tile 0 -> buffer 0
    if (tid == 0) {
      while (atomicAdd(&flags[0], 0) < 64) __builtin_amdgcn_s_sleep(8);
      __threadfence();  // acquire: invalidate local L2 before reading Af/Xft
    }
    __syncthreads();
#pragma unroll
    for (int s = 0; s < 4; s++) {
      async_cp16(ga[s], sm + lo[s]);
      async_cp16(gb[s], sm + 16384 + lo[s]);
    }

    f32x4 acc[4][4] = {};
    for (int t = 0; t < 32; t++) {
      int p = t & 1;
      if (t < 31) {
        if (((t + 1) & 3) == 0) {  // first tile of a new m-chunk: gate it
          if (tid == 0) {
            while (atomicAdd(&flags[(t + 1) >> 2], 0) < 64)
              __builtin_amdgcn_s_sleep(8);
            __threadfence();
          }
          __syncthreads();
        }
        int np = p ^ 1;
#pragma unroll
        for (int s = 0; s < 4; s++) {
          async_cp16(ga[s] + (t + 1) * 64, sm + np * 8192 + lo[s]);
          async_cp16(gb[s] + (t + 1) * 64, sm + 16384 + np * 8192 + lo[s]);
        }
        __builtin_amdgcn_s_waitcnt(0xF78);  // vmcnt(8): tile t landed
      } else {
        __builtin_amdgcn_s_waitcnt(0xF70);  // vmcnt(0): last tile landed
      }
      __builtin_amdgcn_s_barrier();
      const bf16_t* Asp = sm + p * 8192;
      const bf16_t* Bsp = sm + 16384 + p * 8192;
#pragma unroll
      for (int kh = 0; kh < 2; kh++) {
        bf16x8 af[4], bfr[4];
        int c16 = kh * 4 + quad;
#pragma unroll
        for (int i = 0; i < 4; i++) {
          int ra = wn + i * 16 + l16;
          int rb = wh + i * 16 + l16;
          af[i] = *(const bf16x8*)(Asp + ra * 64 + ((c16 ^ (ra & 7)) << 3));
          bfr[i] = *(const bf16x8*)(Bsp + rb * 64 + ((c16 ^ (rb & 7)) << 3));
        }
#pragma unroll
        for (int i = 0; i < 4; i++)
#pragma unroll
          for (int t2 = 0; t2 < 4; t2++)
            acc[i][t2] = __builtin_amdgcn_mfma_f32_16x16x32_bf16(
                af[i], bfr[t2], acc[i][t2], 0, 0, 0);
      }
      __builtin_amdgcn_s_barrier();  // protect buffer p^1 before next DMA
    }
    // C/D layout: col = lane&15, row = quad*4 + reg ; swizzled bf16, ldc=256
#pragma unroll
    for (int i = 0; i < 4; i++) {
#pragma unroll
      for (int t = 0; t < 4; t++) {
        int hc = h0 + wh + t * 16 + l16;
#pragma unroll
        for (int rg = 0; rg < 4; rg++) {
          int nr = n0 + wn + i * 16 + quad * 4 + rg;
          Cj[swz(nr, hc, 256)] = (bf16_t)acc[i][t][rg];
        }
      }
    }
  }
}

// Fused second tensor-product + ifft combine (verified round 4).
// Block = 64x64 out tile (4 waves, 32x32 each). Loop j=0..4: stage C1_j/Wft_j
// 64x256 tiles (double-buffered, counted vmcnt(16)), MFMA K=256, fold C2_j
// into 5 k-accumulators with the cosine matrix, write out directly (mirror).
__global__ __launch_bounds__(256) void gemm_fc(const bf16_t* __restrict__ C1,
                                               const bf16_t* __restrict__ Wf,
                                               float* __restrict__ out) {
  __shared__ bf16_t sm[65536];  // buf p at p*32768: A[64][256] | B at +16384
  const int n0 = blockIdx.x * 64, h0 = blockIdx.y * 64;
  const int tid = threadIdx.x;
  const int wv = tid >> 6, ln = tid & 63;
  const int quad = ln >> 4, l16 = ln & 15;
  const int wn = (wv & 1) * 32, wh = (wv >> 1) * 32;

  const int srow = (tid >> 5), sc8 = (tid & 31) * 8;  // per-thread DMA coords
  const int lbase = wv * 512;                          // wave-uniform lds elems

#define STAGE_J(jj)                                                          \
  {                                                                          \
    const bf16_t* Aj = C1 + (size_t)(jj)*524288 + (size_t)n0 * 256;          \
    const bf16_t* Bj = Wf + (size_t)(jj)*65536 + (size_t)h0 * 256;           \
    bf16_t* da = sm + ((jj)&1) * 32768;                                      \
    bf16_t* db = da + 16384;                                                 \
    _Pragma("unroll") for (int s = 0; s < 8; s++) {                          \
      async_cp16(Aj + (size_t)(s * 8 + srow) * 256 + sc8, da + s * 2048 + lbase); \
      async_cp16(Bj + (size_t)(s * 8 + srow) * 256 + sc8, db + s * 2048 + lbase); \
    }                                                                        \
  }

  const float CKJ[5][5] = {  // CKJ[j][k]: coeff of C2_j in out_k
      {1.f, 1.f, 1.f, 1.f, 1.f},
      {1.f, R2C, 0.f, -R2C, -1.f},
      {1.f, 0.f, -1.f, 0.f, 1.f},
      {1.f, -R2C, 0.f, R2C, -1.f},
      {1.f, -1.f, 1.f, -1.f, 1.f}};

  f32x4 outk[5][2][2] = {};

  STAGE_J(0);
#pragma unroll
  for (int j = 0; j < 5; j++) {
    if (j < 4) {
      STAGE_J(j + 1);
      __builtin_amdgcn_s_waitcnt(0x4F70);  // vmcnt(16): tile j landed
    } else {
      __builtin_amdgcn_s_waitcnt(0xF70);   // vmcnt(0)
    }
    __builtin_amdgcn_s_barrier();
    const bf16_t* Ab = sm + (j & 1) * 32768;
    const bf16_t* Bb = Ab + 16384;
    f32x4 acc[2][2] = {};
#pragma unroll
    for (int kh = 0; kh < 8; kh++) {
      int c16 = kh * 4 + quad;
      int cb = (c16 & ~7) << 3;
      bf16x8 af[2], bfr[2];
#pragma unroll
      for (int i = 0; i < 2; i++) {
        int ra = wn + i * 16 + l16;
        int rb = wh + i * 16 + l16;
        af[i] = *(const bf16x8*)(Ab + ra * 256 + cb + (((c16 & 7) ^ (ra & 7)) << 3));
        bfr[i] = *(const bf16x8*)(Bb + rb * 256 + cb + (((c16 & 7) ^ (rb & 7)) << 3));
      }
#pragma unroll
      for (int i = 0; i < 2; i++)
#pragma unroll
        for (int t = 0; t < 2; t++)
          acc[i][t] = __builtin_amdgcn_mfma_f32_16x16x32_bf16(af[i], bfr[t],
                                                              acc[i][t], 0, 0, 0);
    }
#pragma unroll
    for (int k = 0; k < 5; k++) {
      if (CKJ[j][k] != 0.f) {
#pragma unroll
        for (int i = 0; i < 2; i++)
#pragma unroll
          for (int t = 0; t < 2; t++)
#pragma unroll
            for (int rg = 0; rg < 4; rg++)
              outk[k][i][t][rg] += CKJ[j][k] * acc[i][t][rg];
      }
    }
    __builtin_amdgcn_s_barrier();  // buffer (j+1)&1 reads done before re-stage
  }

  // write out[n][h][0..7]; C/D layout col=lane&15, row=quad*4+reg
#pragma unroll
  for (int i = 0; i < 2; i++) {
#pragma unroll
    for (int rg = 0; rg < 4; rg++) {
      int n = n0 + wn + i * 16 + quad * 4 + rg;
#pragma unroll
      for (int t = 0; t < 2; t++) {
        int h = h0 + wh + t * 16 + l16;
        float c0 = outk[0][i][t][rg], c1 = outk[1][i][t][rg];
        float c2 = outk[2][i][t][rg], c3 = outk[3][i][t][rg];
        float c4 = outk[4][i][t][rg];
        float4* op = (float4*)(out + (size_t)n * 2048 + h * 8);
        op[0] = make_float4(c0, c1, c2, c3);
        op[1] = make_float4(c4, c3, c2, c1);
      }
    }
  }
#undef STAGE_J
}

extern "C" void kernel_launch(void* const* d_in, const int* in_sizes, int n_in,
                              void* d_out, int out_size, void* d_ws, size_t ws_size,
                              hipStream_t stream) {
  const float* X = (const float*)d_in[0];   // (2048,256,8)
  const float* A = (const float*)d_in[1];   // (2048,2048,8)
  const float* W = (const float*)d_in[2];   // (256,256,8)
  float* out = (float*)d_out;               // (2048,256,8)
  char* ws = (char*)d_ws;

  bf16_t* Af  = (bf16_t*)(ws);              // 5*2048*2048*2 = 41943040
  bf16_t* Xft = (bf16_t*)(ws + 41943040);   // 5*256*2048*2  =  5242880
  bf16_t* Wft = (bf16_t*)(ws + 47185920);   // 5*256*256*2   =   655360
  bf16_t* C1  = (bf16_t*)(ws + 47841280);   // 5*2048*256*2  =  5242880
  int* flags  = (int*)   (ws + 53084160);   // 8 ints (chunk counters)

  hipMemsetAsync(flags, 0, 64, stream);
  k_fused<<<dim3(320), 256, 0, stream>>>(X, A, W, Xft, Af, Wft, C1, flags);
  gemm_fc<<<dim3(32, 4), 256, 0, stream>>>(C1, Wft, out);
}

// Round 6
// 251.768 us; speedup vs baseline: 1.3413x; 1.3413x over previous
//
#include <hip/hip_runtime.h>

// MRGCO: real-FFT tensor-product RGCN layer.
// real(fft) along k (len 8) = rank-5 cosine transform (j and 8-j rows equal);
// the ifft->fft round-trip between the two tensor products cancels exactly.
//
// Pipeline (3 kernels) — round-4 structure (253.8 µs), gemm_ring reshaped:
//   k_pre    : A->Af (5 planes, bf16 swizzled, 16B stores), X->Xft, W->Wft
//   gemm_ring: C1_j = Af_j @ Xft_j  (K=2048; 64x128 tile, grid 32x2x5 = 320
//              blocks so ALL 256 CUs are busy — old 128x128 grid was 160
//              blocks leaving 96 CUs idle; 2-deep LDS ring, counted vmcnt(6),
//              48 KB LDS -> 3 blocks/CU so inter-block TLP covers latency)
//   gemm_fc  : out[n][h][k] = sum_j c_jk * (C1_j @ Wft_j)[n][h]  (combine
//              fused into the GEMM epilogue; writes out directly)
//
// Round-5 lesson (reverted): producer/consumer fusion of k_pre+gemm collapsed
// HBM BW to 930 GB/s — 160 producer blocks can't saturate HBM while consumers
// poll. Transform phases need the whole machine.
//
// Swizzle: logical (row r, col c) of a K-contiguous operand stored at
//   r*K + (c&~63) + ((((c>>3)&7) ^ (r&7))<<3) + (c&7)
// so a LINEAR wave-uniform global_load_lds DMA lands tiles in LDS already
// bank-swizzled; ds_read_b128 fragment reads stay conflict-free.

typedef __bf16 bf16_t;
typedef __bf16 bf16x8 __attribute__((ext_vector_type(8)));
typedef float f32x4 __attribute__((ext_vector_type(4)));

#define R2C 0.70710678118654752f

__device__ __forceinline__ size_t swz(int r, int c, int K) {
  return (size_t)r * K + (c & ~63) + ((((c >> 3) & 7) ^ (r & 7)) << 3) + (c & 7);
}

__device__ __forceinline__ void async_cp16(const void* g, void* l) {
  __builtin_amdgcn_global_load_lds((const __attribute__((address_space(1))) char*)g,
                                   (__attribute__((address_space(3))) char*)l,
                                   16, 0, 0);
}

__device__ __forceinline__ void fwd5(const float x[8], float F[5]) {
  float s04 = x[0] + x[4], d04 = x[0] - x[4];
  float s26 = x[2] + x[6];
  float s15 = x[1] + x[5], s37 = x[3] + x[7];
  float t = (x[1] + x[7]) - (x[3] + x[5]);
  float e = s04 + s26, o = s15 + s37;
  F[0] = e + o;
  F[1] = d04 + R2C * t;
  F[2] = s04 - s26;
  F[3] = d04 - R2C * t;
  F[4] = e - o;
}

// Fused input transforms. blocks [0,2048): A ; [2048,2304): X ; [2304,2560): W.
__global__ __launch_bounds__(256) void k_pre(const float* __restrict__ X,
                                             const float* __restrict__ A,
                                             const float* __restrict__ W,
                                             bf16_t* __restrict__ Xft,
                                             bf16_t* __restrict__ Af,
                                             bf16_t* __restrict__ Wft) {
  __shared__ bf16_t tx[40][256];  // X transpose staging: [j*8+h][m]
  int b = blockIdx.x;
  if (b < 2048) {
    // Af[j][n][m] swizzled; 8 consecutive m per thread -> each plane write is
    // one full 16B swizzle chunk (bf16x8), perfectly coalesced.
    size_t t = (size_t)b * 256 + threadIdx.x;
    size_t idx = t * 8;  // n*2048 + m0, m0 multiple of 8
    int n = (int)(idx >> 11), m0 = (int)(idx & 2047);
    const float4* p = (const float4*)(A + idx * 8);
    float F[8][5];
#pragma unroll
    for (int u = 0; u < 8; u++) {
      float4 a = p[2 * u], bq = p[2 * u + 1];
      float x[8] = {a.x, a.y, a.z, a.w, bq.x, bq.y, bq.z, bq.w};
      fwd5(x, F[u]);
    }
    size_t pos = (size_t)n * 2048 + (m0 & ~63) +
                 ((((m0 >> 3) & 7) ^ (n & 7)) << 3);
#pragma unroll
    for (int j = 0; j < 5; j++) {
      bf16x8 v;
#pragma unroll
      for (int u = 0; u < 8; u++) v[u] = (bf16_t)F[u][j];
      *(bf16x8*)(Af + (size_t)j * 4194304 + pos) = v;
    }
  } else if (b < 2304) {
    // Xft[j][h][m]: tile 256 m x 8 h. Coalesced reads -> LDS -> full 16B
    // swizzled chunk writes (no partial-line scatter).
    int bx = b - 2048;
    int m0 = (bx & 7) * 256, h0 = (bx >> 3) * 8;
    int t = threadIdx.x;
    const float4* p = (const float4*)(X + (((size_t)(m0 + t) * 256) + h0) * 8);
#pragma unroll
    for (int h = 0; h < 8; h++) {
      float4 a = p[2 * h], bb = p[2 * h + 1];
      float x[8] = {a.x, a.y, a.z, a.w, bb.x, bb.y, bb.z, bb.w};
      float F[5];
      fwd5(x, F);
#pragma unroll
      for (int j = 0; j < 5; j++) tx[j * 8 + h][t] = (bf16_t)F[j];
    }
    __syncthreads();
#pragma unroll
    for (int it = 0; it < 5; it++) {
      int slot = it * 256 + t;
      int row = slot >> 5, ch = slot & 31;
      int j = row >> 3, hl = row & 7;
      int h = h0 + hl;
      size_t gpos = (size_t)j * 524288 + (size_t)h * 2048 + m0 +
                    ((ch & ~7) << 3) + (((ch & 7) ^ (h & 7)) << 3);
      *(uint4*)(Xft + gpos) = *(const uint4*)(&tx[row][ch * 8]);
    }
  } else {
    // Wft[j][h][h'] = s_j * sum_k W[h'][h][k] c_jk, swizzled (tiny)
    int h = b - 2304;
    int hp = threadIdx.x;
    const float4* p = (const float4*)(W + ((size_t)hp * 256 + h) * 8);
    float4 a = p[0], bb = p[1];
    float x[8] = {a.x, a.y, a.z, a.w, bb.x, bb.y, bb.z, bb.w};
    float F[5];
    fwd5(x, F);
    const float sc[5] = {0.125f, 0.25f, 0.25f, 0.25f, 0.125f};
    size_t pos = swz(h, hp, 256);
#pragma unroll
    for (int j = 0; j < 5; j++)
      Wft[(size_t)j * 65536 + pos] = (bf16_t)(F[j] * sc[j]);
  }
}

// Batched bf16 GEMM, 64x128 tile, BK=64, 4 waves (32x64 each), 16x16x32 MFMA.
// Grid 32x2x5 = 320 blocks (vs 160 for 128x128) -> every CU busy. 2-deep LDS
// ring (48 KB -> 3 blocks/CU); counted vmcnt(6) keeps next tile's 6 DMAs in
// flight across the barrier. Swizzled bf16 output, ldc=256, batch z.
__global__ __launch_bounds__(256) void gemm_ring(const bf16_t* __restrict__ A,
                                                 const bf16_t* __restrict__ B,
                                                 bf16_t* __restrict__ C, int K,
                                                 size_t ap, size_t bp, size_t cp) {
  __shared__ bf16_t sm[24576];  // A ring: 2 x 4096 | B ring at +8192: 2 x 8192
  const int j = blockIdx.z;
  const bf16_t* Aj = A + (size_t)j * ap;
  const bf16_t* Bj = B + (size_t)j * bp;
  bf16_t* Cj = C + (size_t)j * cp;
  const int n0 = blockIdx.x * 64, h0 = blockIdx.y * 128;
  const int tid = threadIdx.x;
  const int wv = tid >> 6, ln = tid & 63;
  const int quad = ln >> 4, l16 = ln & 15;
  const int wn = (wv & 1) * 32, wh = (wv >> 1) * 64;

  const bf16_t* ga[2];
  const bf16_t* gb[4];
  int loa[2], lob[4];  // element offsets inside one ring buffer (wave-uniform)
#pragma unroll
  for (int s = 0; s < 2; s++) {
    int slot = s * 256 + tid;
    int row = slot >> 3, c16 = slot & 7;
    ga[s] = Aj + (size_t)(n0 + row) * K + c16 * 8;
    loa[s] = (s * 256 + wv * 64) * 8;
  }
#pragma unroll
  for (int s = 0; s < 4; s++) {
    int slot = s * 256 + tid;
    int row = slot >> 3, c16 = slot & 7;
    gb[s] = Bj + (size_t)(h0 + row) * K + c16 * 8;
    lob[s] = (s * 256 + wv * 64) * 8;
  }

  const int T = K >> 6;
  // prologue: tile 0 -> buffer 0 (2 A-loads + 4 B-loads)
#pragma unroll
  for (int s = 0; s < 2; s++) async_cp16(ga[s], sm + loa[s]);
#pragma unroll
  for (int s = 0; s < 4; s++) async_cp16(gb[s], sm + 8192 + lob[s]);

  f32x4 acc[2][4] = {};
  for (int t = 0; t < T; t++) {
    int p = t & 1;
    if (t + 1 < T) {
      int np = p ^ 1;
#pragma unroll
      for (int s = 0; s < 2; s++)
        async_cp16(ga[s] + (t + 1) * 64, sm + np * 4096 + loa[s]);
#pragma unroll
      for (int s = 0; s < 4; s++)
        async_cp16(gb[s] + (t + 1) * 64, sm + 8192 + np * 8192 + lob[s]);
      __builtin_amdgcn_s_waitcnt(0xF76);  // vmcnt(6): tile t landed
    } else {
      __builtin_amdgcn_s_waitcnt(0xF70);  // vmcnt(0): last tile landed
    }
    __builtin_amdgcn_s_barrier();
    const bf16_t* Asp = sm + p * 4096;
    const bf16_t* Bsp = sm + 8192 + p * 8192;
#pragma unroll
    for (int kh = 0; kh < 2; kh++) {
      bf16x8 af[2], bfr[4];
      int c16 = kh * 4 + quad;
#pragma unroll
      for (int i = 0; i < 2; i++) {
        int ra = wn + i * 16 + l16;
        af[i] = *(const bf16x8*)(Asp + ra * 64 + ((c16 ^ (ra & 7)) << 3));
      }
#pragma unroll
      for (int i = 0; i < 4; i++) {
        int rb = wh + i * 16 + l16;
        bfr[i] = *(const bf16x8*)(Bsp + rb * 64 + ((c16 ^ (rb & 7)) << 3));
      }
#pragma unroll
      for (int i = 0; i < 2; i++)
#pragma unroll
        for (int t2 = 0; t2 < 4; t2++)
          acc[i][t2] = __builtin_amdgcn_mfma_f32_16x16x32_bf16(af[i], bfr[t2],
                                                               acc[i][t2], 0, 0, 0);
    }
    __builtin_amdgcn_s_barrier();  // protect buffer p^1 before next-iter DMA
  }
  // C/D layout: col = lane&15, row = quad*4 + reg ; swizzled bf16, ldc=256
#pragma unroll
  for (int i = 0; i < 2; i++) {
#pragma unroll
    for (int t = 0; t < 4; t++) {
      int hc = h0 + wh + t * 16 + l16;
#pragma unroll
      for (int rg = 0; rg < 4; rg++) {
        int nr = n0 + wn + i * 16 + quad * 4 + rg;
        Cj[swz(nr, hc, 256)] = (bf16_t)acc[i][t][rg];
      }
    }
  }
}

// Fused second tensor-product + ifft combine (verified round 4).
// Block = 64x64 out tile (4 waves, 32x32 each). Loop j=0..4: stage C1_j/Wft_j
// 64x256 tiles (double-buffered, counted vmcnt(16)), MFMA K=256, fold C2_j
// into 5 k-accumulators with the cosine matrix, write out directly (mirror).
__global__ __launch_bounds__(256) void gemm_fc(const bf16_t* __restrict__ C1,
                                               const bf16_t* __restrict__ Wf,
                                               float* __restrict__ out) {
  __shared__ bf16_t sm[65536];  // buf p at p*32768: A[64][256] | B at +16384
  const int n0 = blockIdx.x * 64, h0 = blockIdx.y * 64;
  const int tid = threadIdx.x;
  const int wv = tid >> 6, ln = tid & 63;
  const int quad = ln >> 4, l16 = ln & 15;
  const int wn = (wv & 1) * 32, wh = (wv >> 1) * 32;

  const int srow = (tid >> 5), sc8 = (tid & 31) * 8;  // per-thread DMA coords
  const int lbase = wv * 512;                          // wave-uniform lds elems

#define STAGE_J(jj)                                                          \
  {                                                                          \
    const bf16_t* Aj = C1 + (size_t)(jj)*524288 + (size_t)n0 * 256;          \
    const bf16_t* Bj = Wf + (size_t)(jj)*65536 + (size_t)h0 * 256;           \
    bf16_t* da = sm + ((jj)&1) * 32768;                                      \
    bf16_t* db = da + 16384;                                                 \
    _Pragma("unroll") for (int s = 0; s < 8; s++) {                          \
      async_cp16(Aj + (size_t)(s * 8 + srow) * 256 + sc8, da + s * 2048 + lbase); \
      async_cp16(Bj + (size_t)(s * 8 + srow) * 256 + sc8, db + s * 2048 + lbase); \
    }                                                                        \
  }

  const float CKJ[5][5] = {  // CKJ[j][k]: coeff of C2_j in out_k
      {1.f, 1.f, 1.f, 1.f, 1.f},
      {1.f, R2C, 0.f, -R2C, -1.f},
      {1.f, 0.f, -1.f, 0.f, 1.f},
      {1.f, -R2C, 0.f, R2C, -1.f},
      {1.f, -1.f, 1.f, -1.f, 1.f}};

  f32x4 outk[5][2][2] = {};

  STAGE_J(0);
#pragma unroll
  for (int j = 0; j < 5; j++) {
    if (j < 4) {
      STAGE_J(j + 1);
      __builtin_amdgcn_s_waitcnt(0x4F70);  // vmcnt(16): tile j landed
    } else {
      __builtin_amdgcn_s_waitcnt(0xF70);   // vmcnt(0)
    }
    __builtin_amdgcn_s_barrier();
    const bf16_t* Ab = sm + (j & 1) * 32768;
    const bf16_t* Bb = Ab + 16384;
    f32x4 acc[2][2] = {};
#pragma unroll
    for (int kh = 0; kh < 8; kh++) {
      int c16 = kh * 4 + quad;
      int cb = (c16 & ~7) << 3;
      bf16x8 af[2], bfr[2];
#pragma unroll
      for (int i = 0; i < 2; i++) {
        int ra = wn + i * 16 + l16;
        int rb = wh + i * 16 + l16;
        af[i] = *(const bf16x8*)(Ab + ra * 256 + cb + (((c16 & 7) ^ (ra & 7)) << 3));
        bfr[i] = *(const bf16x8*)(Bb + rb * 256 + cb + (((c16 & 7) ^ (rb & 7)) << 3));
      }
#pragma unroll
      for (int i = 0; i < 2; i++)
#pragma unroll
        for (int t = 0; t < 2; t++)
          acc[i][t] = __builtin_amdgcn_mfma_f32_16x16x32_bf16(af[i], bfr[t],
                                                              acc[i][t], 0, 0, 0);
    }
#pragma unroll
    for (int k = 0; k < 5; k++) {
      if (CKJ[j][k] != 0.f) {
#pragma unroll
        for (int i = 0; i < 2; i++)
#pragma unroll
          for (int t = 0; t < 2; t++)
#pragma unroll
            for (int rg = 0; rg < 4; rg++)
              outk[k][i][t][rg] += CKJ[j][k] * acc[i][t][rg];
      }
    }
    __builtin_amdgcn_s_barrier();  // buffer (j+1)&1 reads done before re-stage
  }

  // write out[n][h][0..7]; C/D layout col=lane&15, row=quad*4+reg
#pragma unroll
  for (int i = 0; i < 2; i++) {
#pragma unroll
    for (int rg = 0; rg < 4; rg++) {
      int n = n0 + wn + i * 16 + quad * 4 + rg;
#pragma unroll
      for (int t = 0; t < 2; t++) {
        int h = h0 + wh + t * 16 + l16;
        float c0 = outk[0][i][t][rg], c1 = outk[1][i][t][rg];
        float c2 = outk[2][i][t][rg], c3 = outk[3][i][t][rg];
        float c4 = outk[4][i][t][rg];
        float4* op = (float4*)(out + (size_t)n * 2048 + h * 8);
        op[0] = make_float4(c0, c1, c2, c3);
        op[1] = make_float4(c4, c3, c2, c1);
      }
    }
  }
#undef STAGE_J
}

extern "C" void kernel_launch(void* const* d_in, const int* in_sizes, int n_in,
                              void* d_out, int out_size, void* d_ws, size_t ws_size,
                              hipStream_t stream) {
  const float* X = (const float*)d_in[0];   // (2048,256,8)
  const float* A = (const float*)d_in[1];   // (2048,2048,8)
  const float* W = (const float*)d_in[2];   // (256,256,8)
  float* out = (float*)d_out;               // (2048,256,8)
  char* ws = (char*)d_ws;

  bf16_t* Af  = (bf16_t*)(ws);              // 5*2048*2048*2 = 41943040
  bf16_t* Xft = (bf16_t*)(ws + 41943040);   // 5*256*2048*2  =  5242880
  bf16_t* Wft = (bf16_t*)(ws + 47185920);   // 5*256*256*2   =   655360
  bf16_t* C1  = (bf16_t*)(ws + 47841280);   // 5*2048*256*2  =  5242880
                                            // total 53084160 B

  k_pre<<<dim3(2560), 256, 0, stream>>>(X, A, W, Xft, Af, Wft);
  gemm_ring<<<dim3(32, 2, 5), 256, 0, stream>>>(
      Af, Xft, C1, 2048, (size_t)4194304, (size_t)524288, (size_t)524288);
  gemm_fc<<<dim3(32, 4), 256, 0, stream>>>(C1, Wft, out);
}